// Round 2
// baseline (817.793 us; speedup 1.0000x reference)
//
#include <hip/hip_runtime.h>
#include <hip/hip_fp16.h>
#include <cstdint>
#include <cstddef>

#define RR   128
#define VV   (RR * RR * RR)      // 2,097,152 voxels
#define NCH  28
#define CPAD 32                  // pad channels to 32 -> 64 B per voxel (fp16)

__device__ __forceinline__ unsigned short f2h(float f) {
    __half h = __float2half(f);
    return *reinterpret_cast<unsigned short*>(&h);
}
__device__ __forceinline__ float2 up2(unsigned int u) {
    __half2 h = *reinterpret_cast<__half2*>(&u);
    return __half22float2(h);
}

// ---- Kernel 1: vol = base + detail (fp32 in), voxel-major fp16, 32-ch padded ----
// One thread per voxel. All 56 input streams are coalesced dword loads
// (consecutive lanes -> consecutive voxels). Write = 64 B contiguous per thread.
__global__ __launch_bounds__(256) void presum_kernel(
    const float* __restrict__ bden, const float* __restrict__ bsh,
    const float* __restrict__ dden, const float* __restrict__ dsh,
    unsigned short* __restrict__ ws)
{
    int tid = blockIdx.x * 256 + threadIdx.x;
    if (tid >= VV) return;

    unsigned short s[CPAD];
    s[0] = f2h(bden[tid] + dden[tid]);
#pragma unroll
    for (int c = 1; c < NCH; ++c) {
        size_t off = (size_t)(c - 1) * VV + tid;
        s[c] = f2h(bsh[off] + dsh[off]);
    }
#pragma unroll
    for (int c = NCH; c < CPAD; ++c) s[c] = 0;

    uint4* w = (uint4*)(ws + (size_t)tid * CPAD);
#pragma unroll
    for (int q = 0; q < 4; ++q) {
        uint4 v;
        v.x = (unsigned int)s[q*8+0] | ((unsigned int)s[q*8+1] << 16);
        v.y = (unsigned int)s[q*8+2] | ((unsigned int)s[q*8+3] << 16);
        v.z = (unsigned int)s[q*8+4] | ((unsigned int)s[q*8+5] << 16);
        v.w = (unsigned int)s[q*8+6] | ((unsigned int)s[q*8+7] << 16);
        w[q] = v;
    }
}

// ---- Kernel 2: trilinear gather, 4 lanes per point (8 channels each) ----
__global__ __launch_bounds__(256) void gather_kernel(
    const float* __restrict__ xyz,
    const unsigned short* __restrict__ vol,   // padded voxel-major fp16 volume
    float* __restrict__ out, int N)
{
    int tid = blockIdx.x * 256 + threadIdx.x;
    int n = tid >> 2;
    int t = tid & 3;
    if (n >= N) return;

    const float* xp = xyz + (size_t)n * 3;
    // pix = ((x/1.5)+1)*0.5*127 = x*(63.5/1.5) + 63.5
    const float S = 63.5f / 1.5f;
    float px = fmaf(xp[0], S, 63.5f);
    float py = fmaf(xp[1], S, 63.5f);
    float pz = fmaf(xp[2], S, 63.5f);
    float fx0 = floorf(px), fy0 = floorf(py), fz0 = floorf(pz);
    float fx = px - fx0, fy = py - fy0, fz = pz - fz0;
    int ix = (int)fx0, iy = (int)fy0, iz = (int)fz0;
    ix = min(max(ix, 0), RR - 2);
    iy = min(max(iy, 0), RR - 2);
    iz = min(max(iz, 0), RR - 2);

    float wx[2] = {1.0f - fx, fx};
    float wy[2] = {1.0f - fy, fy};
    float wz[2] = {1.0f - fz, fz};

    int ibase = (iz * RR + iy) * RR + ix;
    const char* basep = (const char*)vol + (size_t)t * 16;

    float acc[8];
#pragma unroll
    for (int k = 0; k < 8; ++k) acc[k] = 0.0f;

#pragma unroll
    for (int dz = 0; dz < 2; ++dz)
#pragma unroll
    for (int dy = 0; dy < 2; ++dy)
#pragma unroll
    for (int dx = 0; dx < 2; ++dx) {
        int vidx = ibase + dz * (RR * RR) + dy * RR + dx;
        float w = wz[dz] * wy[dy] * wx[dx];
        const uint4 q = *(const uint4*)(basep + (size_t)vidx * (CPAD * 2));
        float2 p0 = up2(q.x), p1 = up2(q.y), p2 = up2(q.z), p3 = up2(q.w);
        acc[0] = fmaf(w, p0.x, acc[0]);
        acc[1] = fmaf(w, p0.y, acc[1]);
        acc[2] = fmaf(w, p1.x, acc[2]);
        acc[3] = fmaf(w, p1.y, acc[3]);
        acc[4] = fmaf(w, p2.x, acc[4]);
        acc[5] = fmaf(w, p2.y, acc[5]);
        acc[6] = fmaf(w, p3.x, acc[6]);
        acc[7] = fmaf(w, p3.y, acc[7]);
    }

    // out row = 28 fp32 = 112 B (16-B aligned); lane t covers channels [8t, 8t+8)
    float* op = out + (size_t)n * NCH + t * 8;
    if (t < 3) {
        *(float4*)op       = make_float4(acc[0], acc[1], acc[2], acc[3]);
        *(float4*)(op + 4) = make_float4(acc[4], acc[5], acc[6], acc[7]);
    } else {
        *(float4*)op = make_float4(acc[0], acc[1], acc[2], acc[3]); // ch 24..27
    }
}

// ---- Fallback: direct dual-grid gather (used only if ws is too small) ----
__global__ __launch_bounds__(256) void gather_fallback(
    const float* __restrict__ xyz,
    const float* __restrict__ bden, const float* __restrict__ bsh,
    const float* __restrict__ dden, const float* __restrict__ dsh,
    float* __restrict__ out, int N)
{
    int n = blockIdx.x * 256 + threadIdx.x;
    if (n >= N) return;
    const float* xp = xyz + (size_t)n * 3;
    const float S = 63.5f / 1.5f;
    float px = fmaf(xp[0], S, 63.5f);
    float py = fmaf(xp[1], S, 63.5f);
    float pz = fmaf(xp[2], S, 63.5f);
    float fx0 = floorf(px), fy0 = floorf(py), fz0 = floorf(pz);
    float fx = px - fx0, fy = py - fy0, fz = pz - fz0;
    int ix = (int)fx0, iy = (int)fy0, iz = (int)fz0;
    ix = min(max(ix, 0), RR - 2);
    iy = min(max(iy, 0), RR - 2);
    iz = min(max(iz, 0), RR - 2);
    float wx[2] = {1.0f - fx, fx}, wy[2] = {1.0f - fy, fy}, wz[2] = {1.0f - fz, fz};

    int idx[8]; float w[8];
#pragma unroll
    for (int k = 0; k < 8; ++k) {
        int dz = (k >> 2) & 1, dy = (k >> 1) & 1, dx = k & 1;
        idx[k] = ((iz + dz) * RR + (iy + dy)) * RR + (ix + dx);
        w[k] = wz[dz] * wy[dy] * wx[dx];
    }
#pragma unroll
    for (int c = 0; c < NCH; ++c) {
        const float* bp = (c == 0) ? bden : (bsh + (size_t)(c - 1) * VV);
        const float* dp = (c == 0) ? dden : (dsh + (size_t)(c - 1) * VV);
        float a = 0.0f;
#pragma unroll
        for (int k = 0; k < 8; ++k)
            a = fmaf(w[k], bp[idx[k]] + dp[idx[k]], a);
        out[(size_t)n * NCH + c] = a;
    }
}

extern "C" void kernel_launch(void* const* d_in, const int* in_sizes, int n_in,
                              void* d_out, int out_size, void* d_ws, size_t ws_size,
                              hipStream_t stream) {
    const float* xyz  = (const float*)d_in[0];
    const float* bden = (const float*)d_in[1];
    const float* bsh  = (const float*)d_in[2];
    const float* dden = (const float*)d_in[3];
    const float* dsh  = (const float*)d_in[4];
    float* out = (float*)d_out;
    int N = in_sizes[0] / 3;

    size_t need = (size_t)VV * CPAD * sizeof(unsigned short);  // 134 MB
    if (ws_size >= need) {
        presum_kernel<<<(VV + 255) / 256, 256, 0, stream>>>(
            bden, bsh, dden, dsh, (unsigned short*)d_ws);
        long long threads = (long long)N * 4;
        gather_kernel<<<(unsigned int)((threads + 255) / 256), 256, 0, stream>>>(
            xyz, (const unsigned short*)d_ws, out, N);
    } else {
        gather_fallback<<<(N + 255) / 256, 256, 0, stream>>>(
            xyz, bden, bsh, dden, dsh, out, N);
    }
}